// Round 6
// baseline (114.637 us; speedup 1.0000x reference)
//
#include <hip/hip_runtime.h>
#include <hip/hip_bf16.h>

// AttentionHead: B=4, T=4096, D=1024, DA=64, scale = 1/96 folded into q.
// prep_w (W -> K-chunked bf16 Wt2) -> proj (LDS-staged MFMA GEMM, 12 waves,
// K-split) -> attn (256 blocks x 16 waves; block = tile-pair (jt,127-jt) for
// deterministic balance; keys split mod 16; permlane reduces; bf16 combine).

#define T_SEQ 4096

using bf16x8 = __bf16 __attribute__((ext_vector_type(8)));
using f32x16 = float __attribute__((ext_vector_type(16)));
using uint4v = unsigned int __attribute__((ext_vector_type(4)));

// log2(e) / (sqrt(DA) * N_LAYERS): fold softmax scale AND exp->exp2 into q.
static constexpr float QSCALE = 1.4426950408889634f / 96.0f;

// fp32 -> bf16 (RNE) bit math (finite inputs only)
__device__ __forceinline__ unsigned short bf1(float v) {
    unsigned u = __builtin_bit_cast(unsigned, v);
    u += 0x7FFFu + ((u >> 16) & 1u);
    return (unsigned short)(u >> 16);
}
// packed fp32x2 -> bf16x2, single HW instr
__device__ __forceinline__ unsigned cvt2(float lo, float hi) {
    unsigned r;
    asm("v_cvt_pk_bf16_f32 %0, %1, %2" : "=v"(r) : "v"(lo), "v"(hi));
    return r;
}
// v_permlane32_swap: a' = {a.lo32, b.lo32}, b' = {a.hi32, b.hi32}
__device__ __forceinline__ void pswap(unsigned& a, unsigned& b) {
    asm volatile("v_permlane32_swap_b32 %0, %1" : "+v"(a), "+v"(b));
}
// cross-half (lane ^ 32) max/sum without DS pipe
__device__ __forceinline__ float xmax32(float x) {
    unsigned a = __builtin_bit_cast(unsigned, x), b = a;
    pswap(a, b);
    return fmaxf(__builtin_bit_cast(float, a), __builtin_bit_cast(float, b));
}
__device__ __forceinline__ float xsum32(float x) {
    unsigned a = __builtin_bit_cast(unsigned, x), b = a;
    pswap(a, b);
    return __builtin_bit_cast(float, a) + __builtin_bit_cast(float, b);
}
__device__ __forceinline__ float bflo(unsigned u) {
    return __builtin_bit_cast(float, u << 16);
}
__device__ __forceinline__ float bfhi(unsigned u) {
    return __builtin_bit_cast(float, u & 0xFFFF0000u);
}
__device__ __forceinline__ f32x16 zero16() {
    f32x16 z;
#pragma unroll
    for (int i = 0; i < 16; ++i) z[i] = 0.0f;
    return z;
}
#define MFMA32(a, b, c) __builtin_amdgcn_mfma_f32_32x32x16_bf16(a, b, c, 0, 0, 0)

// ---------------- kernel 1: W -> Wt2[kstep16][192 cols][64 k] bf16 ---------
__global__ __launch_bounds__(256) void prep_w(
        const float* __restrict__ Wq, const float* __restrict__ Wk,
        const float* __restrict__ Wv, const float* __restrict__ bq,
        const float* __restrict__ bk, const float* __restrict__ bv,
        unsigned short* __restrict__ Wt2, float* __restrict__ bias_t) {
    __shared__ float tile[64][65];
    const int tid = threadIdx.x;
    const int m = blockIdx.x >> 4, kt = blockIdx.x & 15, d0 = kt * 64;
    const float* W = (m == 0) ? Wq : (m == 1) ? Wk : Wv;
    const int a = tid & 63, r4 = tid >> 6;
#pragma unroll
    for (int j = 0; j < 16; ++j) {
        const int rr = r4 + 4 * j;
        tile[rr][a] = W[(size_t)(d0 + rr) * 64 + a];
    }
    __syncthreads();
    const float scl = (m == 0) ? QSCALE : 1.0f;
    const int dc = tid & 63, ar = tid >> 6;
#pragma unroll
    for (int j = 0; j < 16; ++j) {
        const int aa = ar + 4 * j;
        Wt2[(size_t)kt * 12288 + (size_t)(m * 64 + aa) * 64 + dc] =
            bf1(tile[dc][aa] * scl);
    }
    if (kt == 0 && tid < 64) {
        const float* bb = (m == 0) ? bq : (m == 1) ? bk : bv;
        bias_t[m * 64 + tid] = bb[tid] * scl;
    }
}

// ---------------- kernel 2: QKV projection (LDS-staged MFMA GEMM) ----------
__global__ __launch_bounds__(768) void proj_kernel(
        const float* __restrict__ x, const unsigned short* __restrict__ Wt2,
        const float* __restrict__ bias_t, unsigned short* __restrict__ qs,
        unsigned short* __restrict__ ks, unsigned short* __restrict__ vt) {
    __shared__ unsigned short Ald[2][2][2048];
    __shared__ float Osum[6][64][16];

    const int tid = threadIdx.x;
    const int w = tid >> 6, l = tid & 63, g = l >> 5, c32 = l & 31;
    const int ct = w >> 1, kh = w & 1;
    const int rowbase = blockIdx.x * 32;

    const int si = ct * 64 + l;
    const int r0 = si >> 4, k40 = si & 15;
    const int i1 = si + 384, r1 = i1 >> 4, k41 = i1 & 15;
    const float* xb0 = x + (size_t)(rowbase + r0) * 1024 + kh * 512 + k40 * 4;
    const float* xb1 = x + (size_t)(rowbase + r1) * 1024 + kh * 512 + k41 * 4;
    const int wo0 = r0 * 64 + (((k40 >> 1) ^ (r0 & 7)) << 3) + (k40 & 1) * 4;
    const int wo1 = r1 * 64 + (((k41 >> 1) ^ (r1 & 7)) << 3) + (k41 & 1) * 4;

    const unsigned short* Wb =
        Wt2 + (size_t)(kh * 8) * 12288 + (size_t)(ct * 32 + c32) * 64 + g * 8;
    const int aro = c32 * 64;
    const int as = c32 & 7;

    f32x16 acc = zero16();

    {
        float4 a = *(const float4*)(xb0);
        float4 b4;
        if (si < 128) b4 = *(const float4*)(xb1);
        *(uint2*)(Ald[kh][0] + wo0) = make_uint2(cvt2(a.x, a.y), cvt2(a.z, a.w));
        if (si < 128)
            *(uint2*)(Ald[kh][0] + wo1) = make_uint2(cvt2(b4.x, b4.y), cvt2(b4.z, b4.w));
    }
    __syncthreads();

    int buf = 0;
#pragma unroll
    for (int kt = 0; kt < 8; ++kt) {
        float4 a, b4;
        if (kt < 7) {
            a = *(const float4*)(xb0 + (kt + 1) * 64);
            if (si < 128) b4 = *(const float4*)(xb1 + (kt + 1) * 64);
        }
        const unsigned short* A = Ald[kh][buf];
        const unsigned short* Wkt = Wb + (size_t)kt * 12288;
#pragma unroll
        for (int kk = 0; kk < 4; ++kk) {
            bf16x8 af = *(const bf16x8*)(A + aro + (((kk * 2 + g) ^ as) << 3));
            bf16x8 bfr = *(const bf16x8*)(Wkt + kk * 16);
            acc = MFMA32(af, bfr, acc);
        }
        if (kt < 7) {
            *(uint2*)(Ald[kh][buf ^ 1] + wo0) =
                make_uint2(cvt2(a.x, a.y), cvt2(a.z, a.w));
            if (si < 128)
                *(uint2*)(Ald[kh][buf ^ 1] + wo1) =
                    make_uint2(cvt2(b4.x, b4.y), cvt2(b4.z, b4.w));
        }
        __syncthreads();
        buf ^= 1;
    }

    if (kh == 1) {
#pragma unroll
        for (int r = 0; r < 16; r += 4)
            *(float4*)&Osum[ct][l][r] =
                make_float4(acc[r], acc[r + 1], acc[r + 2], acc[r + 3]);
    }
    __syncthreads();
    if (kh == 1) return;
#pragma unroll
    for (int r = 0; r < 16; ++r) acc[r] += Osum[ct][l][r];

    const int cg = ct * 32 + c32;
    const float bias = bias_t[cg];
    const int mat = cg >> 6, cm = cg & 63;
    if (mat == 2) {
#pragma unroll
        for (int q4 = 0; q4 < 4; ++q4) {
            const int rowg = rowbase + 8 * q4 + 4 * g;
            const int b = rowg >> 12, tl = rowg & (T_SEQ - 1);
            const int c = tl >> 5, t5 = tl & 31;
            unsigned lo = cvt2(acc[4 * q4 + 0] + bias, acc[4 * q4 + 1] + bias);
            unsigned hi = cvt2(acc[4 * q4 + 2] + bias, acc[4 * q4 + 3] + bias);
            *(uint2*)(vt + (((size_t)b * 128 + c) * 64 + cm) * 32 + t5) =
                make_uint2(lo, hi);
        }
    } else {
        unsigned short* dst = (mat == 0) ? qs : ks;
#pragma unroll
        for (int r = 0; r < 16; ++r) {
            const int rowg = rowbase + (r & 3) + 8 * (r >> 2) + 4 * g;
            dst[(size_t)rowg * 64 + cm] = bf1(acc[r] + bias);
        }
    }
}

// ---------------- kernel 3: causal flash attention ----------------
// 256 blocks x 1024 thr (16 waves). Block = batch b + tile pair (127-pid, pid)
// => exactly 129 chunks/block regardless of dispatch. Keys split mod 16.
// S^T = mfma(K, Q); O^T = mfma(V^T, P). Defer-max; permlane cross-half
// reduces; bf16 LDS combine.
__global__ __launch_bounds__(1024) void attn_kernel(
        const unsigned short* __restrict__ qs, const unsigned short* __restrict__ ks,
        const unsigned short* __restrict__ vt, float* __restrict__ out) {
    __shared__ unsigned short Osh[16][32][66];   // bf16 partials, stride 33 words
    __shared__ float msh[16][32];
    __shared__ float ssh[16][32];

    const int tid = threadIdx.x;
    const int w = tid >> 6, l = tid & 63, g = l >> 5, c32 = l & 31;
    const int b = blockIdx.x & 3;        // batch -> dedicated XCDs
    const int pid = blockIdx.x >> 2;     // 0..63

    for (int tt = 0; tt < 2; ++tt) {
        const int jt = tt ? pid : 127 - pid;
        const int qbase = jt * 32;

        // Q fragments
        const unsigned short* qp =
            qs + ((size_t)b * T_SEQ + qbase + c32) * 64 + g * 8;
        bf16x8 qf[4];
#pragma unroll
        for (int t = 0; t < 4; ++t) qf[t] = *(const bf16x8*)(qp + 16 * t);

        const unsigned short* pKc =
            ks + ((size_t)b * T_SEQ + c32) * 64 + g * 8 + (size_t)w * 2048;
        const unsigned short* pVc =
            vt + ((size_t)b * 128 + w) * 2048 + c32 * 32 + g * 8;

        auto loadKV = [&](bf16x8(&kf)[4], bf16x8(&vf)[4]) {
#pragma unroll
            for (int t = 0; t < 4; ++t)
                kf[t] = *(const bf16x8*)(pKc + 16 * t);
#pragma unroll
            for (int mf = 0; mf < 2; ++mf)
#pragma unroll
                for (int kx = 0; kx < 2; ++kx)
                    vf[mf * 2 + kx] = *(const bf16x8*)(pVc + mf * 1024 + kx * 16);
            pKc += 16 * 2048;   // next chunk for this wave (mod-16 split)
            pVc += 16 * 2048;
        };

        const int nch = (jt >= w) ? ((jt - w) >> 4) + 1 : 0;
        const bool hasDiag = ((jt & 15) == w);
        float m = -INFINITY, ssum = 0.0f;
        f32x16 o0 = zero16(), o1 = zero16();
        f32x16 s_cur;
        bf16x8 kA[4], vA[4], kB[4], vB[4];

        if (nch > 0) {
            loadKV(kA, vA);
            if (nch > 1) loadKV(kB, vB);
            s_cur = zero16();
#pragma unroll
            for (int t = 0; t < 4; ++t) s_cur = MFMA32(kA[t], qf[t], s_cur);
        }

        auto STEP = [&](bf16x8(&kc)[4], bf16x8(&vc)[4],
                        bf16x8(&kn)[4], bf16x8(&vn)[4], int i) {
            if (hasDiag && i == nch - 1) {   // diagonal chunk: causal mask
#pragma unroll
                for (int r = 0; r < 16; ++r) {
                    const int kl = (r & 3) + 8 * (r >> 2) + 4 * g;
                    if (kl > c32) s_cur[r] = -1e30f;
                }
            }
            // tree max (max3-friendly) + permlane cross-half
            float a0 = fmaxf(fmaxf(s_cur[0], s_cur[1]), fmaxf(s_cur[2], s_cur[3]));
            float a1 = fmaxf(fmaxf(s_cur[4], s_cur[5]), fmaxf(s_cur[6], s_cur[7]));
            float a2 = fmaxf(fmaxf(s_cur[8], s_cur[9]), fmaxf(s_cur[10], s_cur[11]));
            float a3 = fmaxf(fmaxf(s_cur[12], s_cur[13]), fmaxf(s_cur[14], s_cur[15]));
            float pm = xmax32(fmaxf(fmaxf(a0, a1), fmaxf(a2, a3)));
            if (!__all(pm <= m + 8.0f)) {    // defer-max
                const float mn = fmaxf(m, pm);
                const float alpha = exp2f(m - mn);
#pragma unroll
                for (int r = 0; r < 16; ++r) { o0[r] *= alpha; o1[r] *= alpha; }
                ssum *= alpha;
                m = mn;
            }
            float p[16];
#pragma unroll
            for (int r = 0; r < 16; ++r) p[r] = exp2f(s_cur[r] - m);
            float s0 = (p[0] + p[1]) + (p[2] + p[3]);
            float s1 = (p[4] + p[5]) + (p[6] + p[7]);
            float s2 = (p[8] + p[9]) + (p[10] + p[11]);
            float s3 = (p[12] + p[13]) + (p[14] + p[15]);
            ssum += xsum32((s0 + s1) + (s2 + s3));
            // pack P -> bf16 B-frags (keys lane-local via permlane32_swap)
            unsigned c01 = cvt2(p[0], p[1]), c23 = cvt2(p[2], p[3]);
            unsigned c45 = cvt2(p[4], p[5]), c67 = cvt2(p[6], p[7]);
            pswap(c01, c45); pswap(c23, c67);
            unsigned c89 = cvt2(p[8], p[9]), cab = cvt2(p[10], p[11]);
            unsigned ccd = cvt2(p[12], p[13]), cef = cvt2(p[14], p[15]);
            pswap(c89, ccd); pswap(cab, cef);
            uint4v u0; u0[0] = c01; u0[1] = c23; u0[2] = c45; u0[3] = c67;
            uint4v u1; u1[0] = c89; u1[1] = cab; u1[2] = ccd; u1[3] = cef;
            bf16x8 pb0 = __builtin_bit_cast(bf16x8, u0);
            bf16x8 pb1 = __builtin_bit_cast(bf16x8, u1);
            // QK for next chunk reuses s_cur regs (softmax already consumed them)
            if (i + 1 < nch) {
                f32x16 t = zero16();
#pragma unroll
                for (int t4 = 0; t4 < 4; ++t4) t = MFMA32(kn[t4], qf[t4], t);
                s_cur = t;
            }
            o0 = MFMA32(vc[0], pb0, o0);
            o0 = MFMA32(vc[1], pb1, o0);
            o1 = MFMA32(vc[2], pb0, o1);
            o1 = MFMA32(vc[3], pb1, o1);
            if (i + 2 < nch) loadKV(kc, vc);   // refill freed parity buffers
        };

        int i = 0;
        while (i < nch) {
            STEP(kA, vA, kB, vB, i); ++i;
            if (i < nch) { STEP(kB, vB, kA, vA, i); ++i; }
        }

        // ---- partials -> LDS ----
        if (l < 32) { msh[w][l] = m; ssh[w][l] = ssum; }
#pragma unroll
        for (int q4 = 0; q4 < 4; ++q4) {
            const int base = 8 * q4 + 4 * g;
            *(unsigned*)&Osh[w][c32][base]      = cvt2(o0[4 * q4], o0[4 * q4 + 1]);
            *(unsigned*)&Osh[w][c32][base + 2]  = cvt2(o0[4 * q4 + 2], o0[4 * q4 + 3]);
            *(unsigned*)&Osh[w][c32][base + 32] = cvt2(o1[4 * q4], o1[4 * q4 + 1]);
            *(unsigned*)&Osh[w][c32][base + 34] = cvt2(o1[4 * q4 + 2], o1[4 * q4 + 3]);
        }
        __syncthreads();

        // ---- combine 16 wave-partials (1024 threads: 32 rows x 32 d-pairs) --
        {
            const int qrow = tid >> 5, e = tid & 31;
            float M = -INFINITY;
            float mw[16];
#pragma unroll
            for (int u = 0; u < 16; ++u) { mw[u] = msh[u][qrow]; M = fmaxf(M, mw[u]); }
            float den = 0.0f, r0 = 0.0f, r1 = 0.0f;
#pragma unroll
            for (int u = 0; u < 16; ++u) {
                const float scu = exp2f(mw[u] - M);
                den += ssh[u][qrow] * scu;
                const unsigned uo = *(const unsigned*)&Osh[u][qrow][2 * e];
                r0 += bflo(uo) * scu;
                r1 += bfhi(uo) * scu;
            }
            const float inv = 1.0f / den;
            float2 st; st.x = r0 * inv; st.y = r1 * inv;
            *(float2*)(out + ((size_t)b * T_SEQ + qbase + qrow) * 64 + 2 * e) = st;
        }
        __syncthreads();   // Osh/msh/ssh reused by next tile
    }
}

// ---------------- launch ----------------
extern "C" void kernel_launch(void* const* d_in, const int* in_sizes, int n_in,
                              void* d_out, int out_size, void* d_ws, size_t ws_size,
                              hipStream_t stream) {
    const float* x  = (const float*)d_in[0];
    const float* Wq = (const float*)d_in[1];
    const float* bq = (const float*)d_in[2];
    const float* Wk = (const float*)d_in[3];
    const float* bk = (const float*)d_in[4];
    const float* Wv = (const float*)d_in[5];
    const float* bv = (const float*)d_in[6];
    float* out = (float*)d_out;

    char* ws = (char*)d_ws;
    unsigned short* Wt2    = (unsigned short*)(ws);                 // 384 KB
    float*          bias_t = (float*)(ws + 393216);                 // 768 B
    unsigned short* qsb    = (unsigned short*)(ws + (1u << 20));    // 2 MB
    unsigned short* ksb    = (unsigned short*)(ws + (3u << 20));    // 2 MB
    unsigned short* vtb    = (unsigned short*)(ws + (5u << 20));    // 2 MB

    prep_w<<<48, 256, 0, stream>>>(Wq, Wk, Wv, bq, bk, bv, Wt2, bias_t);
    proj_kernel<<<512, 768, 0, stream>>>(x, Wt2, bias_t, qsb, ksb, vtb);
    attn_kernel<<<256, 1024, 0, stream>>>(qsb, ksb, vtb, out);
}

// Round 8
// 73.930 us; speedup vs baseline: 1.5506x; 1.5506x over previous
//
#include <hip/hip_runtime.h>
#include <hip/hip_bf16.h>

// AttentionHead: B=4, T=4096, D=1024, DA=64, scale = 1/96 folded into q.
// prep_w (W -> K-chunked bf16 Wt2) -> proj (LDS-staged MFMA GEMM, 12 waves,
// K-split) -> attn (256 blocks x 12 waves; block = tile-pair (jt,127-jt);
// keys split mod 12; bf16 combine). R8: cross-half reduces via __shfl_xor —
// R7's xmax32/xsum32 pswap(a,b) with a==b let regalloc coalesce both "+v"
// operands into ONE register (permlane32_swap vN,vN = plain half-swap, not
// a reduce). pswap retained only where operands are distinct (P-pack).

#define T_SEQ 4096
#define NW 12   // attention waves per block

using bf16x8 = __bf16 __attribute__((ext_vector_type(8)));
using f32x16 = float __attribute__((ext_vector_type(16)));
using uint4v = unsigned int __attribute__((ext_vector_type(4)));

// log2(e) / (sqrt(DA) * N_LAYERS): fold softmax scale AND exp->exp2 into q.
static constexpr float QSCALE = 1.4426950408889634f / 96.0f;

// fp32 -> bf16 (RNE) bit math (finite inputs only)
__device__ __forceinline__ unsigned short bf1(float v) {
    unsigned u = __builtin_bit_cast(unsigned, v);
    u += 0x7FFFu + ((u >> 16) & 1u);
    return (unsigned short)(u >> 16);
}
// packed fp32x2 -> bf16x2, single HW instr
__device__ __forceinline__ unsigned cvt2(float lo, float hi) {
    unsigned r;
    asm("v_cvt_pk_bf16_f32 %0, %1, %2" : "=v"(r) : "v"(lo), "v"(hi));
    return r;
}
// v_permlane32_swap: a_lo <-> b_hi. ONLY safe when a,b hold DISTINCT values
// (identical values may be register-coalesced -> degenerate self-swap).
__device__ __forceinline__ void pswap(unsigned& a, unsigned& b) {
    asm volatile("v_permlane32_swap_b32 %0, %1" : "+v"(a), "+v"(b));
}
__device__ __forceinline__ float bflo(unsigned u) {
    return __builtin_bit_cast(float, u << 16);
}
__device__ __forceinline__ float bfhi(unsigned u) {
    return __builtin_bit_cast(float, u & 0xFFFF0000u);
}
__device__ __forceinline__ f32x16 zero16() {
    f32x16 z;
#pragma unroll
    for (int i = 0; i < 16; ++i) z[i] = 0.0f;
    return z;
}
#define MFMA32(a, b, c) __builtin_amdgcn_mfma_f32_32x32x16_bf16(a, b, c, 0, 0, 0)

// ---------------- kernel 1: W -> Wt2[kstep16][192 cols][64 k] bf16 ---------
__global__ __launch_bounds__(256) void prep_w(
        const float* __restrict__ Wq, const float* __restrict__ Wk,
        const float* __restrict__ Wv, const float* __restrict__ bq,
        const float* __restrict__ bk, const float* __restrict__ bv,
        unsigned short* __restrict__ Wt2, float* __restrict__ bias_t) {
    __shared__ float tile[64][65];
    const int tid = threadIdx.x;
    const int m = blockIdx.x >> 4, kt = blockIdx.x & 15, d0 = kt * 64;
    const float* W = (m == 0) ? Wq : (m == 1) ? Wk : Wv;
    const int a = tid & 63, r4 = tid >> 6;
#pragma unroll
    for (int j = 0; j < 16; ++j) {
        const int rr = r4 + 4 * j;
        tile[rr][a] = W[(size_t)(d0 + rr) * 64 + a];
    }
    __syncthreads();
    const float scl = (m == 0) ? QSCALE : 1.0f;
    const int dc = tid & 63, ar = tid >> 6;
#pragma unroll
    for (int j = 0; j < 16; ++j) {
        const int aa = ar + 4 * j;
        Wt2[(size_t)kt * 12288 + (size_t)(m * 64 + aa) * 64 + dc] =
            bf1(tile[dc][aa] * scl);
    }
    if (kt == 0 && tid < 64) {
        const float* bb = (m == 0) ? bq : (m == 1) ? bk : bv;
        bias_t[m * 64 + tid] = bb[tid] * scl;
    }
}

// ---------------- kernel 2: QKV projection (LDS-staged MFMA GEMM) ----------
__global__ __launch_bounds__(768) void proj_kernel(
        const float* __restrict__ x, const unsigned short* __restrict__ Wt2,
        const float* __restrict__ bias_t, unsigned short* __restrict__ qs,
        unsigned short* __restrict__ ks, unsigned short* __restrict__ vt) {
    __shared__ unsigned short Ald[2][2][2048];
    __shared__ float Osum[6][64][16];

    const int tid = threadIdx.x;
    const int w = tid >> 6, l = tid & 63, g = l >> 5, c32 = l & 31;
    const int ct = w >> 1, kh = w & 1;
    const int rowbase = blockIdx.x * 32;

    const int si = ct * 64 + l;
    const int r0 = si >> 4, k40 = si & 15;
    const int i1 = si + 384, r1 = i1 >> 4, k41 = i1 & 15;
    const float* xb0 = x + (size_t)(rowbase + r0) * 1024 + kh * 512 + k40 * 4;
    const float* xb1 = x + (size_t)(rowbase + r1) * 1024 + kh * 512 + k41 * 4;
    const int wo0 = r0 * 64 + (((k40 >> 1) ^ (r0 & 7)) << 3) + (k40 & 1) * 4;
    const int wo1 = r1 * 64 + (((k41 >> 1) ^ (r1 & 7)) << 3) + (k41 & 1) * 4;

    const unsigned short* Wb =
        Wt2 + (size_t)(kh * 8) * 12288 + (size_t)(ct * 32 + c32) * 64 + g * 8;
    const int aro = c32 * 64;
    const int as = c32 & 7;

    f32x16 acc = zero16();

    {
        float4 a = *(const float4*)(xb0);
        float4 b4;
        if (si < 128) b4 = *(const float4*)(xb1);
        *(uint2*)(Ald[kh][0] + wo0) = make_uint2(cvt2(a.x, a.y), cvt2(a.z, a.w));
        if (si < 128)
            *(uint2*)(Ald[kh][0] + wo1) = make_uint2(cvt2(b4.x, b4.y), cvt2(b4.z, b4.w));
    }
    __syncthreads();

    int buf = 0;
#pragma unroll
    for (int kt = 0; kt < 8; ++kt) {
        float4 a, b4;
        if (kt < 7) {
            a = *(const float4*)(xb0 + (kt + 1) * 64);
            if (si < 128) b4 = *(const float4*)(xb1 + (kt + 1) * 64);
        }
        const unsigned short* A = Ald[kh][buf];
        const unsigned short* Wkt = Wb + (size_t)kt * 12288;
#pragma unroll
        for (int kk = 0; kk < 4; ++kk) {
            bf16x8 af = *(const bf16x8*)(A + aro + (((kk * 2 + g) ^ as) << 3));
            bf16x8 bfr = *(const bf16x8*)(Wkt + kk * 16);
            acc = MFMA32(af, bfr, acc);
        }
        if (kt < 7) {
            *(uint2*)(Ald[kh][buf ^ 1] + wo0) =
                make_uint2(cvt2(a.x, a.y), cvt2(a.z, a.w));
            if (si < 128)
                *(uint2*)(Ald[kh][buf ^ 1] + wo1) =
                    make_uint2(cvt2(b4.x, b4.y), cvt2(b4.z, b4.w));
        }
        __syncthreads();
        buf ^= 1;
    }

    if (kh == 1) {
#pragma unroll
        for (int r = 0; r < 16; r += 4)
            *(float4*)&Osum[ct][l][r] =
                make_float4(acc[r], acc[r + 1], acc[r + 2], acc[r + 3]);
    }
    __syncthreads();
    if (kh == 1) return;
#pragma unroll
    for (int r = 0; r < 16; ++r) acc[r] += Osum[ct][l][r];

    const int cg = ct * 32 + c32;
    const float bias = bias_t[cg];
    const int mat = cg >> 6, cm = cg & 63;
    if (mat == 2) {
#pragma unroll
        for (int q4 = 0; q4 < 4; ++q4) {
            const int rowg = rowbase + 8 * q4 + 4 * g;
            const int b = rowg >> 12, tl = rowg & (T_SEQ - 1);
            const int c = tl >> 5, t5 = tl & 31;
            unsigned lo = cvt2(acc[4 * q4 + 0] + bias, acc[4 * q4 + 1] + bias);
            unsigned hi = cvt2(acc[4 * q4 + 2] + bias, acc[4 * q4 + 3] + bias);
            *(uint2*)(vt + (((size_t)b * 128 + c) * 64 + cm) * 32 + t5) =
                make_uint2(lo, hi);
        }
    } else {
        unsigned short* dst = (mat == 0) ? qs : ks;
#pragma unroll
        for (int r = 0; r < 16; ++r) {
            const int rowg = rowbase + (r & 3) + 8 * (r >> 2) + 4 * g;
            dst[(size_t)rowg * 64 + cm] = bf1(acc[r] + bias);
        }
    }
}

// ---------------- kernel 3: causal flash attention ----------------
// 256 blocks x 768 thr (12 waves, 3/SIMD). Block = batch b + tile pair
// (127-pid, pid) => exactly 129 chunks/block. Keys split mod 12.
// S^T = mfma(K, Q); O^T = mfma(V^T, P). Defer-max; __shfl_xor cross-half
// reduces (proven); bf16 LDS combine; 1-ahead K+V register double-buffer.
__global__ __launch_bounds__(768, 3) void attn_kernel(
        const unsigned short* __restrict__ qs, const unsigned short* __restrict__ ks,
        const unsigned short* __restrict__ vt, float* __restrict__ out) {
    __shared__ unsigned short Osh[NW][32][66];   // bf16 partials
    __shared__ float msh[NW][32];
    __shared__ float ssh[NW][32];

    const int tid = threadIdx.x;
    const int w = tid >> 6, l = tid & 63, g = l >> 5, c32 = l & 31;
    const int b = blockIdx.x & 3;        // batch -> spread across XCDs
    const int pid = blockIdx.x >> 2;     // 0..63

    for (int tt = 0; tt < 2; ++tt) {
        const int jt = tt ? pid : 127 - pid;
        const int qbase = jt * 32;

        // Q fragments
        const unsigned short* qp =
            qs + ((size_t)b * T_SEQ + qbase + c32) * 64 + g * 8;
        bf16x8 qf[4];
#pragma unroll
        for (int t = 0; t < 4; ++t) qf[t] = *(const bf16x8*)(qp + 16 * t);

        const unsigned short* pKc =
            ks + ((size_t)b * T_SEQ + c32) * 64 + g * 8 + (size_t)w * 2048;
        const unsigned short* pVc =
            vt + ((size_t)b * 128 + w) * 2048 + c32 * 32 + g * 8;

        auto loadKV = [&](bf16x8(&kf)[4], bf16x8(&vf)[4]) {
#pragma unroll
            for (int t = 0; t < 4; ++t)
                kf[t] = *(const bf16x8*)(pKc + 16 * t);
#pragma unroll
            for (int mf = 0; mf < 2; ++mf)
#pragma unroll
                for (int kx = 0; kx < 2; ++kx)
                    vf[mf * 2 + kx] = *(const bf16x8*)(pVc + mf * 1024 + kx * 16);
            pKc += NW * 2048;   // next chunk for this wave (mod-NW split)
            pVc += NW * 2048;
        };

        const int nch = (jt >= w) ? (jt - w) / NW + 1 : 0;
        const bool hasDiag = (jt >= w) && ((jt - w) % NW == 0);
        float m = -INFINITY, ssum = 0.0f;
        f32x16 o0 = zero16(), o1 = zero16();
        bf16x8 kA[4], vA[4], kB[4], vB[4];

        if (nch > 0) loadKV(kA, vA);

        auto STEP = [&](bf16x8(&kc)[4], bf16x8(&vc)[4],
                        bf16x8(&kn)[4], bf16x8(&vn)[4], int i) {
            if (i + 1 < nch) loadKV(kn, vn);   // prefetch next chunk
            f32x16 s = zero16();
#pragma unroll
            for (int t = 0; t < 4; ++t) s = MFMA32(kc[t], qf[t], s);
            if (hasDiag && i == nch - 1) {     // diagonal chunk: causal mask
#pragma unroll
                for (int r = 0; r < 16; ++r) {
                    const int kl = (r & 3) + 8 * (r >> 2) + 4 * g;
                    if (kl > c32) s[r] = -1e30f;
                }
            }
            // tree max + cross-half (lane^32) via shfl (DS pipe, proven)
            float a0 = fmaxf(fmaxf(s[0], s[1]), fmaxf(s[2], s[3]));
            float a1 = fmaxf(fmaxf(s[4], s[5]), fmaxf(s[6], s[7]));
            float a2 = fmaxf(fmaxf(s[8], s[9]), fmaxf(s[10], s[11]));
            float a3 = fmaxf(fmaxf(s[12], s[13]), fmaxf(s[14], s[15]));
            float pm = fmaxf(fmaxf(a0, a1), fmaxf(a2, a3));
            pm = fmaxf(pm, __shfl_xor(pm, 32, 64));
            if (!__all(pm <= m + 8.0f)) {      // defer-max
                const float mn = fmaxf(m, pm);
                const float alpha = exp2f(m - mn);
#pragma unroll
                for (int r = 0; r < 16; ++r) { o0[r] *= alpha; o1[r] *= alpha; }
                ssum *= alpha;
                m = mn;
            }
            float p[16];
#pragma unroll
            for (int r = 0; r < 16; ++r) p[r] = exp2f(s[r] - m);
            float s0 = (p[0] + p[1]) + (p[2] + p[3]);
            float s1 = (p[4] + p[5]) + (p[6] + p[7]);
            float s2 = (p[8] + p[9]) + (p[10] + p[11]);
            float s3 = (p[12] + p[13]) + (p[14] + p[15]);
            float ps = (s0 + s1) + (s2 + s3);
            ssum += ps + __shfl_xor(ps, 32, 64);
            // pack P -> bf16 B-frags (pswap operands all DISTINCT values)
            unsigned c01 = cvt2(p[0], p[1]), c23 = cvt2(p[2], p[3]);
            unsigned c45 = cvt2(p[4], p[5]), c67 = cvt2(p[6], p[7]);
            pswap(c01, c45); pswap(c23, c67);
            unsigned c89 = cvt2(p[8], p[9]), cab = cvt2(p[10], p[11]);
            unsigned ccd = cvt2(p[12], p[13]), cef = cvt2(p[14], p[15]);
            pswap(c89, ccd); pswap(cab, cef);
            uint4v u0; u0[0] = c01; u0[1] = c23; u0[2] = c45; u0[3] = c67;
            uint4v u1; u1[0] = c89; u1[1] = cab; u1[2] = ccd; u1[3] = cef;
            bf16x8 pb0 = __builtin_bit_cast(bf16x8, u0);
            bf16x8 pb1 = __builtin_bit_cast(bf16x8, u1);
            o0 = MFMA32(vc[0], pb0, o0);
            o0 = MFMA32(vc[1], pb1, o0);
            o1 = MFMA32(vc[2], pb0, o1);
            o1 = MFMA32(vc[3], pb1, o1);
        };

        int i = 0;
        while (i < nch) {
            STEP(kA, vA, kB, vB, i); ++i;
            if (i < nch) { STEP(kB, vB, kA, vA, i); ++i; }
        }

        // ---- partials -> LDS ----
        if (l < 32) { msh[w][l] = m; ssh[w][l] = ssum; }
#pragma unroll
        for (int q4 = 0; q4 < 4; ++q4) {
            const int base = 8 * q4 + 4 * g;
            *(unsigned*)&Osh[w][c32][base]      = cvt2(o0[4 * q4], o0[4 * q4 + 1]);
            *(unsigned*)&Osh[w][c32][base + 2]  = cvt2(o0[4 * q4 + 2], o0[4 * q4 + 3]);
            *(unsigned*)&Osh[w][c32][base + 32] = cvt2(o1[4 * q4], o1[4 * q4 + 1]);
            *(unsigned*)&Osh[w][c32][base + 34] = cvt2(o1[4 * q4 + 2], o1[4 * q4 + 3]);
        }
        __syncthreads();

        // ---- combine NW wave-partials (512 active: 32 rows x 16 d-quads) ----
        if (tid < 512) {
            const int qrow = tid >> 4, e4 = tid & 15;
            float M = -INFINITY;
            float mw[NW];
#pragma unroll
            for (int u = 0; u < NW; ++u) { mw[u] = msh[u][qrow]; M = fmaxf(M, mw[u]); }
            float den = 0.0f;
            float r0 = 0.f, r1 = 0.f, r2 = 0.f, r3 = 0.f;
#pragma unroll
            for (int u = 0; u < NW; ++u) {
                const float scu = exp2f(mw[u] - M);
                den += ssh[u][qrow] * scu;
                const unsigned ua = *(const unsigned*)&Osh[u][qrow][4 * e4];
                const unsigned ub = *(const unsigned*)&Osh[u][qrow][4 * e4 + 2];
                r0 += bflo(ua) * scu;
                r1 += bfhi(ua) * scu;
                r2 += bflo(ub) * scu;
                r3 += bfhi(ub) * scu;
            }
            const float inv = 1.0f / den;
            float4 st;
            st.x = r0 * inv; st.y = r1 * inv; st.z = r2 * inv; st.w = r3 * inv;
            *(float4*)(out + ((size_t)b * T_SEQ + qbase + qrow) * 64 + 4 * e4) = st;
        }
        __syncthreads();   // Osh/msh/ssh reused by next tile
    }
}

// ---------------- launch ----------------
extern "C" void kernel_launch(void* const* d_in, const int* in_sizes, int n_in,
                              void* d_out, int out_size, void* d_ws, size_t ws_size,
                              hipStream_t stream) {
    const float* x  = (const float*)d_in[0];
    const float* Wq = (const float*)d_in[1];
    const float* bq = (const float*)d_in[2];
    const float* Wk = (const float*)d_in[3];
    const float* bk = (const float*)d_in[4];
    const float* Wv = (const float*)d_in[5];
    const float* bv = (const float*)d_in[6];
    float* out = (float*)d_out;

    char* ws = (char*)d_ws;
    unsigned short* Wt2    = (unsigned short*)(ws);                 // 384 KB
    float*          bias_t = (float*)(ws + 393216);                 // 768 B
    unsigned short* qsb    = (unsigned short*)(ws + (1u << 20));    // 2 MB
    unsigned short* ksb    = (unsigned short*)(ws + (3u << 20));    // 2 MB
    unsigned short* vtb    = (unsigned short*)(ws + (5u << 20));    // 2 MB

    prep_w<<<48, 256, 0, stream>>>(Wq, Wk, Wv, bq, bk, bv, Wt2, bias_t);
    proj_kernel<<<512, 768, 0, stream>>>(x, Wt2, bias_t, qsb, ksb, vtb);
    attn_kernel<<<256, 768, 0, stream>>>(qsb, ksb, vtb, out);
}

// Round 9
// 69.339 us; speedup vs baseline: 1.6533x; 1.0662x over previous
//
#include <hip/hip_runtime.h>
#include <hip/hip_bf16.h>

// AttentionHead: B=4, T=4096, D=1024, DA=64, scale = 1/96 folded into q.
// prep_w (W -> K-chunked bf16 Wt2) -> proj (LDS-staged MFMA GEMM) ->
// attn (256 blocks x 12 waves; tile-pair per block; keys mod 12).
// R9: s_cur QK pipeline (QK of chunk i+1 independent of softmax of i),
// single time-shared V buffer (reg-safe at 3 waves/SIMD, cap 170),
// per-lane defer check + per-lane ssum (shfl only once per tile / on
// rescale path), setprio around MFMA clusters.

#define T_SEQ 4096
#define NW 12   // attention waves per block

using bf16x8 = __bf16 __attribute__((ext_vector_type(8)));
using f32x16 = float __attribute__((ext_vector_type(16)));
using uint4v = unsigned int __attribute__((ext_vector_type(4)));

// log2(e) / (sqrt(DA) * N_LAYERS): fold softmax scale AND exp->exp2 into q.
static constexpr float QSCALE = 1.4426950408889634f / 96.0f;

// fp32 -> bf16 (RNE) bit math (finite inputs only)
__device__ __forceinline__ unsigned short bf1(float v) {
    unsigned u = __builtin_bit_cast(unsigned, v);
    u += 0x7FFFu + ((u >> 16) & 1u);
    return (unsigned short)(u >> 16);
}
// packed fp32x2 -> bf16x2, single HW instr
__device__ __forceinline__ unsigned cvt2(float lo, float hi) {
    unsigned r;
    asm("v_cvt_pk_bf16_f32 %0, %1, %2" : "=v"(r) : "v"(lo), "v"(hi));
    return r;
}
// v_permlane32_swap: a_lo <-> b_hi. ONLY safe when a,b hold DISTINCT values
// (identical values may be register-coalesced -> degenerate self-swap).
__device__ __forceinline__ void pswap(unsigned& a, unsigned& b) {
    asm volatile("v_permlane32_swap_b32 %0, %1" : "+v"(a), "+v"(b));
}
__device__ __forceinline__ float bflo(unsigned u) {
    return __builtin_bit_cast(float, u << 16);
}
__device__ __forceinline__ float bfhi(unsigned u) {
    return __builtin_bit_cast(float, u & 0xFFFF0000u);
}
__device__ __forceinline__ f32x16 zero16() {
    f32x16 z;
#pragma unroll
    for (int i = 0; i < 16; ++i) z[i] = 0.0f;
    return z;
}
#define MFMA32(a, b, c) __builtin_amdgcn_mfma_f32_32x32x16_bf16(a, b, c, 0, 0, 0)

// ---------------- kernel 1: W -> Wt2[kstep16][192 cols][64 k] bf16 ---------
__global__ __launch_bounds__(256) void prep_w(
        const float* __restrict__ Wq, const float* __restrict__ Wk,
        const float* __restrict__ Wv, const float* __restrict__ bq,
        const float* __restrict__ bk, const float* __restrict__ bv,
        unsigned short* __restrict__ Wt2, float* __restrict__ bias_t) {
    __shared__ float tile[64][65];
    const int tid = threadIdx.x;
    const int m = blockIdx.x >> 4, kt = blockIdx.x & 15, d0 = kt * 64;
    const float* W = (m == 0) ? Wq : (m == 1) ? Wk : Wv;
    const int a = tid & 63, r4 = tid >> 6;
#pragma unroll
    for (int j = 0; j < 16; ++j) {
        const int rr = r4 + 4 * j;
        tile[rr][a] = W[(size_t)(d0 + rr) * 64 + a];
    }
    __syncthreads();
    const float scl = (m == 0) ? QSCALE : 1.0f;
    const int dc = tid & 63, ar = tid >> 6;
#pragma unroll
    for (int j = 0; j < 16; ++j) {
        const int aa = ar + 4 * j;
        Wt2[(size_t)kt * 12288 + (size_t)(m * 64 + aa) * 64 + dc] =
            bf1(tile[dc][aa] * scl);
    }
    if (kt == 0 && tid < 64) {
        const float* bb = (m == 0) ? bq : (m == 1) ? bk : bv;
        bias_t[m * 64 + tid] = bb[tid] * scl;
    }
}

// ---------------- kernel 2: QKV projection (LDS-staged MFMA GEMM) ----------
__global__ __launch_bounds__(768) void proj_kernel(
        const float* __restrict__ x, const unsigned short* __restrict__ Wt2,
        const float* __restrict__ bias_t, unsigned short* __restrict__ qs,
        unsigned short* __restrict__ ks, unsigned short* __restrict__ vt) {
    __shared__ unsigned short Ald[2][2][2048];
    __shared__ float Osum[6][64][16];

    const int tid = threadIdx.x;
    const int w = tid >> 6, l = tid & 63, g = l >> 5, c32 = l & 31;
    const int ct = w >> 1, kh = w & 1;
    const int rowbase = blockIdx.x * 32;

    const int si = ct * 64 + l;
    const int r0 = si >> 4, k40 = si & 15;
    const int i1 = si + 384, r1 = i1 >> 4, k41 = i1 & 15;
    const float* xb0 = x + (size_t)(rowbase + r0) * 1024 + kh * 512 + k40 * 4;
    const float* xb1 = x + (size_t)(rowbase + r1) * 1024 + kh * 512 + k41 * 4;
    const int wo0 = r0 * 64 + (((k40 >> 1) ^ (r0 & 7)) << 3) + (k40 & 1) * 4;
    const int wo1 = r1 * 64 + (((k41 >> 1) ^ (r1 & 7)) << 3) + (k41 & 1) * 4;

    const unsigned short* Wb =
        Wt2 + (size_t)(kh * 8) * 12288 + (size_t)(ct * 32 + c32) * 64 + g * 8;
    const int aro = c32 * 64;
    const int as = c32 & 7;

    f32x16 acc = zero16();

    {
        float4 a = *(const float4*)(xb0);
        float4 b4;
        if (si < 128) b4 = *(const float4*)(xb1);
        *(uint2*)(Ald[kh][0] + wo0) = make_uint2(cvt2(a.x, a.y), cvt2(a.z, a.w));
        if (si < 128)
            *(uint2*)(Ald[kh][0] + wo1) = make_uint2(cvt2(b4.x, b4.y), cvt2(b4.z, b4.w));
    }
    __syncthreads();

    int buf = 0;
#pragma unroll
    for (int kt = 0; kt < 8; ++kt) {
        float4 a, b4;
        if (kt < 7) {
            a = *(const float4*)(xb0 + (kt + 1) * 64);
            if (si < 128) b4 = *(const float4*)(xb1 + (kt + 1) * 64);
        }
        const unsigned short* A = Ald[kh][buf];
        const unsigned short* Wkt = Wb + (size_t)kt * 12288;
#pragma unroll
        for (int kk = 0; kk < 4; ++kk) {
            bf16x8 af = *(const bf16x8*)(A + aro + (((kk * 2 + g) ^ as) << 3));
            bf16x8 bfr = *(const bf16x8*)(Wkt + kk * 16);
            acc = MFMA32(af, bfr, acc);
        }
        if (kt < 7) {
            *(uint2*)(Ald[kh][buf ^ 1] + wo0) =
                make_uint2(cvt2(a.x, a.y), cvt2(a.z, a.w));
            if (si < 128)
                *(uint2*)(Ald[kh][buf ^ 1] + wo1) =
                    make_uint2(cvt2(b4.x, b4.y), cvt2(b4.z, b4.w));
        }
        __syncthreads();
        buf ^= 1;
    }

    if (kh == 1) {
#pragma unroll
        for (int r = 0; r < 16; r += 4)
            *(float4*)&Osum[ct][l][r] =
                make_float4(acc[r], acc[r + 1], acc[r + 2], acc[r + 3]);
    }
    __syncthreads();
    if (kh == 1) return;
#pragma unroll
    for (int r = 0; r < 16; ++r) acc[r] += Osum[ct][l][r];

    const int cg = ct * 32 + c32;
    const float bias = bias_t[cg];
    const int mat = cg >> 6, cm = cg & 63;
    if (mat == 2) {
#pragma unroll
        for (int q4 = 0; q4 < 4; ++q4) {
            const int rowg = rowbase + 8 * q4 + 4 * g;
            const int b = rowg >> 12, tl = rowg & (T_SEQ - 1);
            const int c = tl >> 5, t5 = tl & 31;
            unsigned lo = cvt2(acc[4 * q4 + 0] + bias, acc[4 * q4 + 1] + bias);
            unsigned hi = cvt2(acc[4 * q4 + 2] + bias, acc[4 * q4 + 3] + bias);
            *(uint2*)(vt + (((size_t)b * 128 + c) * 64 + cm) * 32 + t5) =
                make_uint2(lo, hi);
        }
    } else {
        unsigned short* dst = (mat == 0) ? qs : ks;
#pragma unroll
        for (int r = 0; r < 16; ++r) {
            const int rowg = rowbase + (r & 3) + 8 * (r >> 2) + 4 * g;
            dst[(size_t)rowg * 64 + cm] = bf1(acc[r] + bias);
        }
    }
}

// ---------------- kernel 3: causal flash attention ----------------
// 256 blocks x 768 thr (12 waves, 3/SIMD). Block = batch b + tile pair
// (127-pid, pid). Keys split mod 12. s_cur pipeline: QK of chunk i+1
// computed at end of step i (independent of softmax of i). K double-
// buffered, V single time-shared buffer. Per-lane defer check; per-lane
// ssum (one shfl per tile). setprio(1) around MFMA clusters.
__global__ __launch_bounds__(768, 3) void attn_kernel(
        const unsigned short* __restrict__ qs, const unsigned short* __restrict__ ks,
        const unsigned short* __restrict__ vt, float* __restrict__ out) {
    __shared__ unsigned short Osh[NW][32][66];   // bf16 partials
    __shared__ float msh[NW][32];
    __shared__ float ssh[NW][32];

    const int tid = threadIdx.x;
    const int w = tid >> 6, l = tid & 63, g = l >> 5, c32 = l & 31;
    const int b = blockIdx.x & 3;        // batch -> spread across XCDs
    const int pid = blockIdx.x >> 2;     // 0..63

    for (int tt = 0; tt < 2; ++tt) {
        const int jt = tt ? pid : 127 - pid;
        const int qbase = jt * 32;

        // Q fragments
        const unsigned short* qp =
            qs + ((size_t)b * T_SEQ + qbase + c32) * 64 + g * 8;
        bf16x8 qf[4];
#pragma unroll
        for (int t = 0; t < 4; ++t) qf[t] = *(const bf16x8*)(qp + 16 * t);

        const unsigned short* pKc =
            ks + ((size_t)b * T_SEQ + c32) * 64 + g * 8 + (size_t)w * 2048;
        const unsigned short* pVc =
            vt + ((size_t)b * 128 + w) * 2048 + c32 * 32 + g * 8;

        auto loadK = [&](bf16x8(&kf)[4]) {
#pragma unroll
            for (int t = 0; t < 4; ++t)
                kf[t] = *(const bf16x8*)(pKc + 16 * t);
            pKc += NW * 2048;
        };
        auto loadV = [&](bf16x8(&vf)[4]) {
#pragma unroll
            for (int mf = 0; mf < 2; ++mf)
#pragma unroll
                for (int kx = 0; kx < 2; ++kx)
                    vf[mf * 2 + kx] = *(const bf16x8*)(pVc + mf * 1024 + kx * 16);
            pVc += NW * 2048;
        };

        const int nch = (jt >= w) ? (jt - w) / NW + 1 : 0;
        const bool hasDiag = (jt >= w) && ((jt - w) % NW == 0);
        float m = -INFINITY, ssum = 0.0f;   // ssum is PER-LANE (half-row)
        f32x16 o0 = zero16(), o1 = zero16();
        f32x16 s_cur;
        bf16x8 k0[4], k1[4], vR[4];

        if (nch > 0) {
            loadK(k0);
            f32x16 t = zero16();
#pragma unroll
            for (int t4 = 0; t4 < 4; ++t4) t = MFMA32(k0[t4], qf[t4], t);
            s_cur = t;
        }

        auto STEP = [&](bf16x8(&kn)[4], int i) {
            loadV(vR);                       // V_i (first: PV waits vmcnt(4))
            if (i + 1 < nch) loadK(kn);      // K_{i+1} (in flight until QK)
            if (hasDiag && i == nch - 1) {   // diagonal chunk: causal mask
#pragma unroll
                for (int r = 0; r < 16; ++r) {
                    const int kl = (r & 3) + 8 * (r >> 2) + 4 * g;
                    if (kl > c32) s_cur[r] = -1e30f;
                }
            }
            // per-lane (half-row) max; row-max shfl only on rescale path
            float a0 = fmaxf(fmaxf(s_cur[0], s_cur[1]), fmaxf(s_cur[2], s_cur[3]));
            float a1 = fmaxf(fmaxf(s_cur[4], s_cur[5]), fmaxf(s_cur[6], s_cur[7]));
            float a2 = fmaxf(fmaxf(s_cur[8], s_cur[9]), fmaxf(s_cur[10], s_cur[11]));
            float a3 = fmaxf(fmaxf(s_cur[12], s_cur[13]), fmaxf(s_cur[14], s_cur[15]));
            float pm = fmaxf(fmaxf(a0, a1), fmaxf(a2, a3));
            if (!__all(pm <= m + 8.0f)) {    // defer-max (rare path)
                float rmax = fmaxf(pm, __shfl_xor(pm, 32, 64));  // row max
                const float mn = fmaxf(m, rmax);
                const float alpha = exp2f(m - mn);
#pragma unroll
                for (int r = 0; r < 16; ++r) { o0[r] *= alpha; o1[r] *= alpha; }
                ssum *= alpha;
                m = mn;
            }
            float p[16];
#pragma unroll
            for (int r = 0; r < 16; ++r) p[r] = exp2f(s_cur[r] - m);
            float s0 = (p[0] + p[1]) + (p[2] + p[3]);
            float s1 = (p[4] + p[5]) + (p[6] + p[7]);
            float s2 = (p[8] + p[9]) + (p[10] + p[11]);
            float s3 = (p[12] + p[13]) + (p[14] + p[15]);
            ssum += (s0 + s1) + (s2 + s3);   // per-lane accumulate, no shfl
            // pack P -> bf16 B-frags (pswap operands all DISTINCT values)
            unsigned c01 = cvt2(p[0], p[1]), c23 = cvt2(p[2], p[3]);
            unsigned c45 = cvt2(p[4], p[5]), c67 = cvt2(p[6], p[7]);
            pswap(c01, c45); pswap(c23, c67);
            unsigned c89 = cvt2(p[8], p[9]), cab = cvt2(p[10], p[11]);
            unsigned ccd = cvt2(p[12], p[13]), cef = cvt2(p[14], p[15]);
            pswap(c89, ccd); pswap(cab, cef);
            uint4v u0; u0[0] = c01; u0[1] = c23; u0[2] = c45; u0[3] = c67;
            uint4v u1; u1[0] = c89; u1[1] = cab; u1[2] = ccd; u1[3] = cef;
            bf16x8 pb0 = __builtin_bit_cast(bf16x8, u0);
            bf16x8 pb1 = __builtin_bit_cast(bf16x8, u1);
            __builtin_amdgcn_s_setprio(1);
            o0 = MFMA32(vR[0], pb0, o0);
            o0 = MFMA32(vR[1], pb1, o0);
            o1 = MFMA32(vR[2], pb0, o1);
            o1 = MFMA32(vR[3], pb1, o1);
            if (i + 1 < nch) {               // QK next chunk (indep of softmax)
                f32x16 t = zero16();
#pragma unroll
                for (int t4 = 0; t4 < 4; ++t4) t = MFMA32(kn[t4], qf[t4], t);
                s_cur = t;
            }
            __builtin_amdgcn_s_setprio(0);
        };

        int i = 0;
        while (i < nch) {
            STEP(k1, i); ++i;
            if (i < nch) { STEP(k0, i); ++i; }
        }
        ssum += __shfl_xor(ssum, 32, 64);    // one cross-half combine per tile

        // ---- partials -> LDS ----
        if (l < 32) { msh[w][l] = m; ssh[w][l] = ssum; }
#pragma unroll
        for (int q4 = 0; q4 < 4; ++q4) {
            const int base = 8 * q4 + 4 * g;
            *(unsigned*)&Osh[w][c32][base]      = cvt2(o0[4 * q4], o0[4 * q4 + 1]);
            *(unsigned*)&Osh[w][c32][base + 2]  = cvt2(o0[4 * q4 + 2], o0[4 * q4 + 3]);
            *(unsigned*)&Osh[w][c32][base + 32] = cvt2(o1[4 * q4], o1[4 * q4 + 1]);
            *(unsigned*)&Osh[w][c32][base + 34] = cvt2(o1[4 * q4 + 2], o1[4 * q4 + 3]);
        }
        __syncthreads();

        // ---- combine NW wave-partials (512 active: 32 rows x 16 d-quads) ----
        if (tid < 512) {
            const int qrow = tid >> 4, e4 = tid & 15;
            float M = -INFINITY;
            float mw[NW];
#pragma unroll
            for (int u = 0; u < NW; ++u) { mw[u] = msh[u][qrow]; M = fmaxf(M, mw[u]); }
            float den = 0.0f;
            float r0 = 0.f, r1 = 0.f, r2 = 0.f, r3 = 0.f;
#pragma unroll
            for (int u = 0; u < NW; ++u) {
                const float scu = exp2f(mw[u] - M);
                den += ssh[u][qrow] * scu;
                const unsigned ua = *(const unsigned*)&Osh[u][qrow][4 * e4];
                const unsigned ub = *(const unsigned*)&Osh[u][qrow][4 * e4 + 2];
                r0 += bflo(ua) * scu;
                r1 += bfhi(ua) * scu;
                r2 += bflo(ub) * scu;
                r3 += bfhi(ub) * scu;
            }
            const float inv = 1.0f / den;
            float4 st;
            st.x = r0 * inv; st.y = r1 * inv; st.z = r2 * inv; st.w = r3 * inv;
            *(float4*)(out + ((size_t)b * T_SEQ + qbase + qrow) * 64 + 4 * e4) = st;
        }
        __syncthreads();   // Osh/msh/ssh reused by next tile
    }
}

// ---------------- launch ----------------
extern "C" void kernel_launch(void* const* d_in, const int* in_sizes, int n_in,
                              void* d_out, int out_size, void* d_ws, size_t ws_size,
                              hipStream_t stream) {
    const float* x  = (const float*)d_in[0];
    const float* Wq = (const float*)d_in[1];
    const float* bq = (const float*)d_in[2];
    const float* Wk = (const float*)d_in[3];
    const float* bk = (const float*)d_in[4];
    const float* Wv = (const float*)d_in[5];
    const float* bv = (const float*)d_in[6];
    float* out = (float*)d_out;

    char* ws = (char*)d_ws;
    unsigned short* Wt2    = (unsigned short*)(ws);                 // 384 KB
    float*          bias_t = (float*)(ws + 393216);                 // 768 B
    unsigned short* qsb    = (unsigned short*)(ws + (1u << 20));    // 2 MB
    unsigned short* ksb    = (unsigned short*)(ws + (3u << 20));    // 2 MB
    unsigned short* vtb    = (unsigned short*)(ws + (5u << 20));    // 2 MB

    prep_w<<<48, 256, 0, stream>>>(Wq, Wk, Wv, bq, bk, bv, Wt2, bias_t);
    proj_kernel<<<512, 768, 0, stream>>>(x, Wt2, bias_t, qsb, ksb, vtb);
    attn_kernel<<<256, 768, 0, stream>>>(qsb, ksb, vtb, out);
}

// Round 10
// 69.070 us; speedup vs baseline: 1.6597x; 1.0039x over previous
//
#include <hip/hip_runtime.h>
#include <hip/hip_bf16.h>

// AttentionHead: B=4, T=4096, D=1024, DA=64, scale = 1/96 folded into q.
// R10 (proj only): pad-68 A-tile (kills 8-way ds_read conflict), Osum
// stride 20 (kills 16-way combine conflict), counted-vmcnt staging with
// raw s_barrier + lgkmcnt(0) (x loads stay in flight across barriers).

#define T_SEQ 4096
#define NW 12   // attention waves per block

using bf16x8 = __bf16 __attribute__((ext_vector_type(8)));
using f32x16 = float __attribute__((ext_vector_type(16)));
using uint4v = unsigned int __attribute__((ext_vector_type(4)));

static constexpr float QSCALE = 1.4426950408889634f / 96.0f;

__device__ __forceinline__ unsigned short bf1(float v) {
    unsigned u = __builtin_bit_cast(unsigned, v);
    u += 0x7FFFu + ((u >> 16) & 1u);
    return (unsigned short)(u >> 16);
}
__device__ __forceinline__ unsigned cvt2(float lo, float hi) {
    unsigned r;
    asm("v_cvt_pk_bf16_f32 %0, %1, %2" : "=v"(r) : "v"(lo), "v"(hi));
    return r;
}
// v_permlane32_swap: ONLY safe when a,b hold DISTINCT values (see R8 note).
__device__ __forceinline__ void pswap(unsigned& a, unsigned& b) {
    asm volatile("v_permlane32_swap_b32 %0, %1" : "+v"(a), "+v"(b));
}
__device__ __forceinline__ float bflo(unsigned u) {
    return __builtin_bit_cast(float, u << 16);
}
__device__ __forceinline__ float bfhi(unsigned u) {
    return __builtin_bit_cast(float, u & 0xFFFF0000u);
}
__device__ __forceinline__ f32x16 zero16() {
    f32x16 z;
#pragma unroll
    for (int i = 0; i < 16; ++i) z[i] = 0.0f;
    return z;
}
#define MFMA32(a, b, c) __builtin_amdgcn_mfma_f32_32x32x16_bf16(a, b, c, 0, 0, 0)

// ---------------- kernel 1: W -> Wt2[kstep16][192 cols][64 k] bf16 ---------
__global__ __launch_bounds__(256) void prep_w(
        const float* __restrict__ Wq, const float* __restrict__ Wk,
        const float* __restrict__ Wv, const float* __restrict__ bq,
        const float* __restrict__ bk, const float* __restrict__ bv,
        unsigned short* __restrict__ Wt2, float* __restrict__ bias_t) {
    __shared__ float tile[64][65];
    const int tid = threadIdx.x;
    const int m = blockIdx.x >> 4, kt = blockIdx.x & 15, d0 = kt * 64;
    const float* W = (m == 0) ? Wq : (m == 1) ? Wk : Wv;
    const int a = tid & 63, r4 = tid >> 6;
#pragma unroll
    for (int j = 0; j < 16; ++j) {
        const int rr = r4 + 4 * j;
        tile[rr][a] = W[(size_t)(d0 + rr) * 64 + a];
    }
    __syncthreads();
    const float scl = (m == 0) ? QSCALE : 1.0f;
    const int dc = tid & 63, ar = tid >> 6;
#pragma unroll
    for (int j = 0; j < 16; ++j) {
        const int aa = ar + 4 * j;
        Wt2[(size_t)kt * 12288 + (size_t)(m * 64 + aa) * 64 + dc] =
            bf1(tile[dc][aa] * scl);
    }
    if (kt == 0 && tid < 64) {
        const float* bb = (m == 0) ? bq : (m == 1) ? bk : bv;
        bias_t[m * 64 + tid] = bb[tid] * scl;
    }
}

// ---------------- kernel 2: QKV projection (LDS-staged MFMA GEMM) ----------
// 512 blocks x 768 thr = 12 waves (ct 0..5, kh 0..1). 32 rows/block.
// A-tile rows padded to 68 shorts (conflict-free write AND b128 read).
// Per stage: B loads -> LDS write (prev x regs, counted vmcnt) -> issue
// kt+2 x loads -> ds_read+MFMA -> lgkmcnt(0) + raw barrier (x loads stay
// in flight across the barrier; LDS-only cross-wave data).
__global__ __launch_bounds__(768) void proj_kernel(
        const float* __restrict__ x, const unsigned short* __restrict__ Wt2,
        const float* __restrict__ bias_t, unsigned short* __restrict__ qs,
        unsigned short* __restrict__ ks, unsigned short* __restrict__ vt) {
    __shared__ unsigned short Ald[2][2][2176];   // [kh][buf][32 rows x 68]
    __shared__ float Osum[6][64][20];            // kh=1 partials, stride 20

    const int tid = threadIdx.x;
    const int w = tid >> 6, l = tid & 63, g = l >> 5, c32 = l & 31;
    const int ct = w >> 1, kh = w & 1;
    const int rowbase = blockIdx.x * 32;

    const int si = ct * 64 + l;
    const int r0 = si >> 4, k40 = si & 15;
    const int i1 = si + 384, r1 = i1 >> 4, k41 = i1 & 15;
    const bool haveB = (si < 128);
    const float* xb0 = x + (size_t)(rowbase + r0) * 1024 + kh * 512 + k40 * 4;
    const float* xb1 = x + (size_t)(rowbase + r1) * 1024 + kh * 512 + k41 * 4;
    const int wo0 = r0 * 68 + k40 * 4;
    const int wo1 = r1 * 68 + k41 * 4;

    const unsigned short* Wb =
        Wt2 + (size_t)(kh * 8) * 12288 + (size_t)(ct * 32 + c32) * 64 + g * 8;
    const int aro = c32 * 68;

    f32x16 acc = zero16();
    float4 ra, rb;

    // prologue: kt=0 -> buf0; issue kt=1 loads (stay in flight over barrier)
    ra = *(const float4*)(xb0);
    if (haveB) rb = *(const float4*)(xb1);
    *(uint2*)(Ald[kh][0] + wo0) = make_uint2(cvt2(ra.x, ra.y), cvt2(ra.z, ra.w));
    if (haveB)
        *(uint2*)(Ald[kh][0] + wo1) = make_uint2(cvt2(rb.x, rb.y), cvt2(rb.z, rb.w));
    ra = *(const float4*)(xb0 + 64);
    if (haveB) rb = *(const float4*)(xb1 + 64);
    asm volatile("s_waitcnt lgkmcnt(0)" ::: "memory");
    __builtin_amdgcn_s_barrier();
    __builtin_amdgcn_sched_barrier(0);

    int buf = 0;
#pragma unroll
    for (int kt = 0; kt < 8; ++kt) {
        const unsigned short* A = Ald[kh][buf];
        const unsigned short* Wkt = Wb + (size_t)kt * 12288;
        // (0) B loads first (consumed this stage; counted wait excludes x)
        bf16x8 b0 = *(const bf16x8*)(Wkt);
        bf16x8 b1 = *(const bf16x8*)(Wkt + 16);
        bf16x8 b2 = *(const bf16x8*)(Wkt + 32);
        bf16x8 b3 = *(const bf16x8*)(Wkt + 48);
        // (a) write kt+1 x data (regs loaded a full stage ago)
        if (kt < 7) {
            *(uint2*)(Ald[kh][buf ^ 1] + wo0) =
                make_uint2(cvt2(ra.x, ra.y), cvt2(ra.z, ra.w));
            if (haveB)
                *(uint2*)(Ald[kh][buf ^ 1] + wo1) =
                    make_uint2(cvt2(rb.x, rb.y), cvt2(rb.z, rb.w));
        }
        // (b) issue kt+2 x loads (in flight across the barrier)
        if (kt < 6) {
            ra = *(const float4*)(xb0 + (kt + 2) * 64);
            if (haveB) rb = *(const float4*)(xb1 + (kt + 2) * 64);
        }
        // (c) ds_read + MFMA (waits B loads only, not the fresh x loads)
        {
            bf16x8 a0 = *(const bf16x8*)(A + aro + (0 + g) * 8);
            bf16x8 a1 = *(const bf16x8*)(A + aro + (2 + g) * 8);
            bf16x8 a2 = *(const bf16x8*)(A + aro + (4 + g) * 8);
            bf16x8 a3 = *(const bf16x8*)(A + aro + (6 + g) * 8);
            acc = MFMA32(a0, b0, acc);
            acc = MFMA32(a1, b1, acc);
            acc = MFMA32(a2, b2, acc);
            acc = MFMA32(a3, b3, acc);
        }
        asm volatile("s_waitcnt lgkmcnt(0)" ::: "memory");
        __builtin_amdgcn_s_barrier();
        __builtin_amdgcn_sched_barrier(0);
        buf ^= 1;
    }

    // combine K-halves (Osum stride 20: bank-bijective, 16B-aligned)
    if (kh == 1) {
#pragma unroll
        for (int r = 0; r < 16; r += 4)
            *(float4*)&Osum[ct][l][r] =
                make_float4(acc[r], acc[r + 1], acc[r + 2], acc[r + 3]);
    }
    __syncthreads();
    if (kh == 1) return;
#pragma unroll
    for (int r = 0; r < 16; r += 4) {
        float4 o4 = *(const float4*)&Osum[ct][l][r];
        acc[r] += o4.x; acc[r + 1] += o4.y; acc[r + 2] += o4.z; acc[r + 3] += o4.w;
    }

    const int cg = ct * 32 + c32;
    const float bias = bias_t[cg];
    const int mat = cg >> 6, cm = cg & 63;
    if (mat == 2) {
#pragma unroll
        for (int q4 = 0; q4 < 4; ++q4) {
            const int rowg = rowbase + 8 * q4 + 4 * g;
            const int b = rowg >> 12, tl = rowg & (T_SEQ - 1);
            const int c = tl >> 5, t5 = tl & 31;
            unsigned lo = cvt2(acc[4 * q4 + 0] + bias, acc[4 * q4 + 1] + bias);
            unsigned hi = cvt2(acc[4 * q4 + 2] + bias, acc[4 * q4 + 3] + bias);
            *(uint2*)(vt + (((size_t)b * 128 + c) * 64 + cm) * 32 + t5) =
                make_uint2(lo, hi);
        }
    } else {
        unsigned short* dst = (mat == 0) ? qs : ks;
#pragma unroll
        for (int r = 0; r < 16; ++r) {
            const int rowg = rowbase + (r & 3) + 8 * (r >> 2) + 4 * g;
            dst[(size_t)rowg * 64 + cm] = bf1(acc[r] + bias);
        }
    }
}

// ---------------- kernel 3: causal flash attention (unchanged from R9) ----
__global__ __launch_bounds__(768, 3) void attn_kernel(
        const unsigned short* __restrict__ qs, const unsigned short* __restrict__ ks,
        const unsigned short* __restrict__ vt, float* __restrict__ out) {
    __shared__ unsigned short Osh[NW][32][66];
    __shared__ float msh[NW][32];
    __shared__ float ssh[NW][32];

    const int tid = threadIdx.x;
    const int w = tid >> 6, l = tid & 63, g = l >> 5, c32 = l & 31;
    const int b = blockIdx.x & 3;
    const int pid = blockIdx.x >> 2;

    for (int tt = 0; tt < 2; ++tt) {
        const int jt = tt ? pid : 127 - pid;
        const int qbase = jt * 32;

        const unsigned short* qp =
            qs + ((size_t)b * T_SEQ + qbase + c32) * 64 + g * 8;
        bf16x8 qf[4];
#pragma unroll
        for (int t = 0; t < 4; ++t) qf[t] = *(const bf16x8*)(qp + 16 * t);

        const unsigned short* pKc =
            ks + ((size_t)b * T_SEQ + c32) * 64 + g * 8 + (size_t)w * 2048;
        const unsigned short* pVc =
            vt + ((size_t)b * 128 + w) * 2048 + c32 * 32 + g * 8;

        auto loadK = [&](bf16x8(&kf)[4]) {
#pragma unroll
            for (int t = 0; t < 4; ++t)
                kf[t] = *(const bf16x8*)(pKc + 16 * t);
            pKc += NW * 2048;
        };
        auto loadV = [&](bf16x8(&vf)[4]) {
#pragma unroll
            for (int mf = 0; mf < 2; ++mf)
#pragma unroll
                for (int kx = 0; kx < 2; ++kx)
                    vf[mf * 2 + kx] = *(const bf16x8*)(pVc + mf * 1024 + kx * 16);
            pVc += NW * 2048;
        };

        const int nch = (jt >= w) ? (jt - w) / NW + 1 : 0;
        const bool hasDiag = (jt >= w) && ((jt - w) % NW == 0);
        float m = -INFINITY, ssum = 0.0f;
        f32x16 o0 = zero16(), o1 = zero16();
        f32x16 s_cur;
        bf16x8 k0[4], k1[4], vR[4];

        if (nch > 0) {
            loadK(k0);
            f32x16 t = zero16();
#pragma unroll
            for (int t4 = 0; t4 < 4; ++t4) t = MFMA32(k0[t4], qf[t4], t);
            s_cur = t;
        }

        auto STEP = [&](bf16x8(&kn)[4], int i) {
            loadV(vR);
            if (i + 1 < nch) loadK(kn);
            if (hasDiag && i == nch - 1) {
#pragma unroll
                for (int r = 0; r < 16; ++r) {
                    const int kl = (r & 3) + 8 * (r >> 2) + 4 * g;
                    if (kl > c32) s_cur[r] = -1e30f;
                }
            }
            float a0 = fmaxf(fmaxf(s_cur[0], s_cur[1]), fmaxf(s_cur[2], s_cur[3]));
            float a1 = fmaxf(fmaxf(s_cur[4], s_cur[5]), fmaxf(s_cur[6], s_cur[7]));
            float a2 = fmaxf(fmaxf(s_cur[8], s_cur[9]), fmaxf(s_cur[10], s_cur[11]));
            float a3 = fmaxf(fmaxf(s_cur[12], s_cur[13]), fmaxf(s_cur[14], s_cur[15]));
            float pm = fmaxf(fmaxf(a0, a1), fmaxf(a2, a3));
            if (!__all(pm <= m + 8.0f)) {
                float rmax = fmaxf(pm, __shfl_xor(pm, 32, 64));
                const float mn = fmaxf(m, rmax);
                const float alpha = exp2f(m - mn);
#pragma unroll
                for (int r = 0; r < 16; ++r) { o0[r] *= alpha; o1[r] *= alpha; }
                ssum *= alpha;
                m = mn;
            }
            float p[16];
#pragma unroll
            for (int r = 0; r < 16; ++r) p[r] = exp2f(s_cur[r] - m);
            float s0 = (p[0] + p[1]) + (p[2] + p[3]);
            float s1 = (p[4] + p[5]) + (p[6] + p[7]);
            float s2 = (p[8] + p[9]) + (p[10] + p[11]);
            float s3 = (p[12] + p[13]) + (p[14] + p[15]);
            ssum += (s0 + s1) + (s2 + s3);
            unsigned c01 = cvt2(p[0], p[1]), c23 = cvt2(p[2], p[3]);
            unsigned c45 = cvt2(p[4], p[5]), c67 = cvt2(p[6], p[7]);
            pswap(c01, c45); pswap(c23, c67);
            unsigned c89 = cvt2(p[8], p[9]), cab = cvt2(p[10], p[11]);
            unsigned ccd = cvt2(p[12], p[13]), cef = cvt2(p[14], p[15]);
            pswap(c89, ccd); pswap(cab, cef);
            uint4v u0; u0[0] = c01; u0[1] = c23; u0[2] = c45; u0[3] = c67;
            uint4v u1; u1[0] = c89; u1[1] = cab; u1[2] = ccd; u1[3] = cef;
            bf16x8 pb0 = __builtin_bit_cast(bf16x8, u0);
            bf16x8 pb1 = __builtin_bit_cast(bf16x8, u1);
            __builtin_amdgcn_s_setprio(1);
            o0 = MFMA32(vR[0], pb0, o0);
            o0 = MFMA32(vR[1], pb1, o0);
            o1 = MFMA32(vR[2], pb0, o1);
            o1 = MFMA32(vR[3], pb1, o1);
            if (i + 1 < nch) {
                f32x16 t = zero16();
#pragma unroll
                for (int t4 = 0; t4 < 4; ++t4) t = MFMA32(kn[t4], qf[t4], t);
                s_cur = t;
            }
            __builtin_amdgcn_s_setprio(0);
        };

        int i = 0;
        while (i < nch) {
            STEP(k1, i); ++i;
            if (i < nch) { STEP(k0, i); ++i; }
        }
        ssum += __shfl_xor(ssum, 32, 64);

        if (l < 32) { msh[w][l] = m; ssh[w][l] = ssum; }
#pragma unroll
        for (int q4 = 0; q4 < 4; ++q4) {
            const int base = 8 * q4 + 4 * g;
            *(unsigned*)&Osh[w][c32][base]      = cvt2(o0[4 * q4], o0[4 * q4 + 1]);
            *(unsigned*)&Osh[w][c32][base + 2]  = cvt2(o0[4 * q4 + 2], o0[4 * q4 + 3]);
            *(unsigned*)&Osh[w][c32][base + 32] = cvt2(o1[4 * q4], o1[4 * q4 + 1]);
            *(unsigned*)&Osh[w][c32][base + 34] = cvt2(o1[4 * q4 + 2], o1[4 * q4 + 3]);
        }
        __syncthreads();

        if (tid < 512) {
            const int qrow = tid >> 4, e4 = tid & 15;
            float M = -INFINITY;
            float mw[NW];
#pragma unroll
            for (int u = 0; u < NW; ++u) { mw[u] = msh[u][qrow]; M = fmaxf(M, mw[u]); }
            float den = 0.0f;
            float r0 = 0.f, r1 = 0.f, r2 = 0.f, r3 = 0.f;
#pragma unroll
            for (int u = 0; u < NW; ++u) {
                const float scu = exp2f(mw[u] - M);
                den += ssh[u][qrow] * scu;
                const unsigned ua = *(const unsigned*)&Osh[u][qrow][4 * e4];
                const unsigned ub = *(const unsigned*)&Osh[u][qrow][4 * e4 + 2];
                r0 += bflo(ua) * scu;
                r1 += bfhi(ua) * scu;
                r2 += bflo(ub) * scu;
                r3 += bfhi(ub) * scu;
            }
            const float inv = 1.0f / den;
            float4 st;
            st.x = r0 * inv; st.y = r1 * inv; st.z = r2 * inv; st.w = r3 * inv;
            *(float4*)(out + ((size_t)b * T_SEQ + qbase + qrow) * 64 + 4 * e4) = st;
        }
        __syncthreads();
    }
}

// ---------------- launch ----------------
extern "C" void kernel_launch(void* const* d_in, const int* in_sizes, int n_in,
                              void* d_out, int out_size, void* d_ws, size_t ws_size,
                              hipStream_t stream) {
    const float* x  = (const float*)d_in[0];
    const float* Wq = (const float*)d_in[1];
    const float* bq = (const float*)d_in[2];
    const float* Wk = (const float*)d_in[3];
    const float* bk = (const float*)d_in[4];
    const float* Wv = (const float*)d_in[5];
    const float* bv = (const float*)d_in[6];
    float* out = (float*)d_out;

    char* ws = (char*)d_ws;
    unsigned short* Wt2    = (unsigned short*)(ws);                 // 384 KB
    float*          bias_t = (float*)(ws + 393216);                 // 768 B
    unsigned short* qsb    = (unsigned short*)(ws + (1u << 20));    // 2 MB
    unsigned short* ksb    = (unsigned short*)(ws + (3u << 20));    // 2 MB
    unsigned short* vtb    = (unsigned short*)(ws + (5u << 20));    // 2 MB

    prep_w<<<48, 256, 0, stream>>>(Wq, Wk, Wv, bq, bk, bv, Wt2, bias_t);
    proj_kernel<<<512, 768, 0, stream>>>(x, Wt2, bias_t, qsb, ksb, vtb);
    attn_kernel<<<256, 768, 0, stream>>>(qsb, ksb, vtb, out);
}